// Round 1
// baseline (891.263 us; speedup 1.0000x reference)
//
#include <hip/hip_runtime.h>
#include <cstddef>

#define TT 256
#define HH 128
#define EST 132    // E row stride: b128 reads land 8 dwords on every bank = balanced
#define SCPS 260   // scp row stride: 16B-aligned rows, banks balanced

__device__ __forceinline__ float rdlane(float v, int l) {
  return __int_as_float(__builtin_amdgcn_readlane(__float_as_int(v), l));
}
__device__ __forceinline__ float fast_sigmoid(float x) {
  const float L2E = 1.4426950408889634f;
  float y = __builtin_amdgcn_exp2f(-x * L2E);
  return __builtin_amdgcn_rcpf(1.0f + y);
}
__device__ __forceinline__ float fast_tanh(float x) {
  const float C2 = 2.8853900817779268f;   // 2*log2(e)
  float y = __builtin_amdgcn_exp2f(x * C2);
  return 1.0f - 2.0f * __builtin_amdgcn_rcpf(1.0f + y);
}

// One workgroup per batch element; 1024 threads = 16 waves (4/SIMD).
// LDS (158.75 KB) pins 1 WG/CU, so 4 waves/SIMD is the occupancy; register
// budget is a hard 128/wave (512-entry unified file / 4 waves). Partition is
// chosen so the persistent set fits: wr2[32] float2 (64) + w2loc[16] (16) +
// gate consts (12) + misc ~ 100.
__global__ __attribute__((amdgpu_flat_work_group_size(1024, 1024),
                          amdgpu_waves_per_eu(4, 4)))
void decoder_kernel(const float* __restrict__ x,
                    const float* __restrict__ enc_output,
                    const float* __restrict__ h0,
                    const float* __restrict__ c0,
                    const float* __restrict__ W1,
                    const float* __restrict__ W2,
                    const float* __restrict__ V,
                    const float* __restrict__ Wk,
                    const float* __restrict__ Wr,
                    const float* __restrict__ bias,
                    float* __restrict__ out)
{
  __shared__ float E[TT * EST];      // 135168 B : exp2(C2 * enc_proj)
  __shared__ float zpart[4 * 512];   // 8192 B   : h@Wr k-quarter partials
  __shared__ float scp[16 * SCPS];   // 16640 B  : phase-D partials [koctet][t]
  __shared__ float hbuf[HH];         // 512 B
  __shared__ float xlds[2 * TT];     // 2048 B   : x pairs (ptr lookup)
  // total 162560 B <= 160 KiB

  const int u    = threadIdx.x;
  const int b    = blockIdx.x;
  const int lane = u & 63;
  const int w    = u >> 6;           // wave 0..15 (owns k in [8w,8w+8) for C/D)
  const float C2  = 2.8853900817779268f;
  const float L2E = 1.4426950408889634f;

  // ---------------- P0: enc_proj = enc_output[b] @ W1 -> E (raw) ----------------
  {
    const float* encb = enc_output + (size_t)b * TT * HH;
    const int tsub = u >> 4;          // 0..63
    const int ks   = (u & 15) * 8;
    for (int p = 0; p < 4; ++p) {
      const int tt = p * 64 + tsub;
      float4 a0 = {0.f, 0.f, 0.f, 0.f};
      float4 a1 = {0.f, 0.f, 0.f, 0.f};
      const float4* er4 = (const float4*)(encb + tt * HH);
      for (int j4 = 0; j4 < 32; ++j4) {
        const float4 ev = er4[j4];
        const float* w1p = W1 + (j4 * 4) * HH + ks;
        float4 wa, wb;
        wa = *(const float4*)(w1p + 0 * HH); wb = *(const float4*)(w1p + 0 * HH + 4);
        a0.x += ev.x * wa.x; a0.y += ev.x * wa.y; a0.z += ev.x * wa.z; a0.w += ev.x * wa.w;
        a1.x += ev.x * wb.x; a1.y += ev.x * wb.y; a1.z += ev.x * wb.z; a1.w += ev.x * wb.w;
        wa = *(const float4*)(w1p + 1 * HH); wb = *(const float4*)(w1p + 1 * HH + 4);
        a0.x += ev.y * wa.x; a0.y += ev.y * wa.y; a0.z += ev.y * wa.z; a0.w += ev.y * wa.w;
        a1.x += ev.y * wb.x; a1.y += ev.y * wb.y; a1.z += ev.y * wb.z; a1.w += ev.y * wb.w;
        wa = *(const float4*)(w1p + 2 * HH); wb = *(const float4*)(w1p + 2 * HH + 4);
        a0.x += ev.z * wa.x; a0.y += ev.z * wa.y; a0.z += ev.z * wa.z; a0.w += ev.z * wa.w;
        a1.x += ev.z * wb.x; a1.y += ev.z * wb.y; a1.z += ev.z * wb.z; a1.w += ev.z * wb.w;
        wa = *(const float4*)(w1p + 3 * HH); wb = *(const float4*)(w1p + 3 * HH + 4);
        a0.x += ev.w * wa.x; a0.y += ev.w * wa.y; a0.z += ev.w * wa.z; a0.w += ev.w * wa.w;
        a1.x += ev.w * wb.x; a1.y += ev.w * wb.y; a1.z += ev.w * wb.z; a1.w += ev.w * wb.w;
      }
      *(float4*)(&E[tt * EST + ks])     = a0;
      *(float4*)(&E[tt * EST + ks + 4]) = a1;
    }
    if (u < 2 * TT) xlds[u] = x[b * (TT * 2) + u];
  }

  // ---------------- persistent registers ----------------
  // Apre: thread (kq = u>>8, cs2 = u&255) owns cols 2cs2..2cs2+1, k in [32kq,+32)
  const int kq  = u >> 8;            // wave-uniform (w>>2)
  const int cs2 = u & 255;
  float2 wr2[32];
  #pragma unroll
  for (int i = 0; i < 32; ++i)
    wr2[i] = *(const float2*)(Wr + (size_t)(32 * kq + i) * 512 + 2 * cs2);
  // Gates: lanes 0..31 of waves 0..3 own unit m = 32w+lane (SIMD-balanced)
  const int m = 32 * (w & 3) + (lane & 31);
  float wkA[4], wkB[4], bbg[4];
  #pragma unroll
  for (int gg = 0; gg < 4; ++gg) {
    wkA[gg] = Wk[gg * HH + m];
    wkB[gg] = Wk[512 + gg * HH + m];
    bbg[gg] = bias[gg * HH + m];
  }
  float c = c0[b * HH + m];
  // Phase C (wave-local k-octet): lane -> kk8 = lane&7, jq8 = lane>>3 (8-way j)
  const int kk8 = lane & 7;
  const int jq8 = lane >> 3;
  float w2loc[16];                   // W2[16jq8+i][8w+kk8]
  #pragma unroll
  for (int i = 0; i < 16; ++i)
    w2loc[i] = W2[(16 * jq8 + i) * HH + 8 * w + kk8];
  // Phase D: v2 for k = 8w+i via loop-invariant readlane (SGPR-resident)
  const float v2r = -2.0f * V[8 * w + kk8];
  float vL[8];
  #pragma unroll
  for (int i = 0; i < 8; ++i) vL[i] = rdlane(v2r, i);
  float ptr0 = 1.0f, ptr1 = 1.0f;
  float svr;
  {
    float v = V[lane] + V[64 + lane];
    #pragma unroll
    for (int o = 1; o < 64; o <<= 1) v += __shfl_xor(v, o, 64);
    svr = v;
  }

  __syncthreads();   // P0 staging + xlds visible

  // ---------------- P1: E = exp2(C2 * enc_proj) in place (own chunks) ----------
  {
    float* Er = &E[(u >> 2) * EST + 32 * (u & 3)];
    #pragma unroll
    for (int i = 0; i < 8; ++i) {
      float4 ev = *(const float4*)(Er + 4 * i);
      ev.x = __builtin_amdgcn_exp2f(ev.x * C2);
      ev.y = __builtin_amdgcn_exp2f(ev.y * C2);
      ev.z = __builtin_amdgcn_exp2f(ev.z * C2);
      ev.w = __builtin_amdgcn_exp2f(ev.w * C2);
      *(float4*)(Er + 4 * i) = ev;
    }
  }
  // prologue Apre: zpart = h0 @ Wr (h0 from global; hbuf untouched -> no race)
  {
    float hA0 = h0[(size_t)b * HH + 32 * kq + (lane & 31)];
    float2 zac = {0.f, 0.f};
    #pragma unroll
    for (int i = 0; i < 32; ++i) {
      float hi = rdlane(hA0, i);
      zac.x += hi * wr2[i].x;
      zac.y += hi * wr2[i].y;
    }
    *(float2*)(&zpart[kq * 512 + 2 * cs2]) = zac;
  }
  __syncthreads();   // E final + zpart(h0) visible

  float* outb = out + (size_t)b * TT * TT;

  // ---------------- step loop: 2 barriers ----------------
  #pragma unroll 1
  for (int step = 0; step < TT; ++step) {
    // ==== R window ====
    if (step > 0) {
      if (w < 4) {
        // ---- argmax path (critical): reduce -> mx -> ballot -> ptr -> gates ----
        float4 sc = {0.f, 0.f, 0.f, 0.f};
        #pragma unroll
        for (int q = 0; q < 16; ++q) {
          const float4 v = *(const float4*)(&scp[q * SCPS + 4 * lane]);
          sc.x += v.x; sc.y += v.y; sc.z += v.z; sc.w += v.w;
        }
        float m4 = fmaxf(fmaxf(sc.x, sc.y), fmaxf(sc.z, sc.w));
        int ttl = (sc.x == m4) ? 0 : (sc.y == m4) ? 1 : (sc.z == m4) ? 2 : 3;
        float mx = m4;
        #pragma unroll
        for (int o = 1; o < 64; o <<= 1) mx = fmaxf(mx, __shfl_xor(mx, o));
        unsigned long long bal = __ballot(m4 == mx);
        int ls  = __ffsll(bal) - 1;            // first-max lane = lowest t block
        int tc  = 4 * lane + ttl;
        int tts = __builtin_amdgcn_readlane(tc, ls);   // wave-uniform winner t
        const float2 pp = *(const float2*)(&xlds[2 * tts]);  // uniform broadcast
        ptr0 = pp.x;
        ptr1 = pp.y;
      } else if (w < 8) {
        // ---- softmax path (off critical): p -> ws -> out-row store ----
        float4 sc = {0.f, 0.f, 0.f, 0.f};
        #pragma unroll
        for (int q = 0; q < 16; ++q) {
          const float4 v = *(const float4*)(&scp[q * SCPS + 4 * lane]);
          sc.x += v.x; sc.y += v.y; sc.z += v.z; sc.w += v.w;
        }
        sc.x += svr; sc.y += svr; sc.z += svr; sc.w += svr;
        float p0 = __builtin_amdgcn_exp2f((sc.x - 12.0f) * L2E);
        float p1 = __builtin_amdgcn_exp2f((sc.y - 12.0f) * L2E);
        float p2 = __builtin_amdgcn_exp2f((sc.z - 12.0f) * L2E);
        float p3 = __builtin_amdgcn_exp2f((sc.w - 12.0f) * L2E);
        float ws4 = (p0 + p1) + (p2 + p3);
        #pragma unroll
        for (int o = 1; o < 64; o <<= 1) ws4 += __shfl_xor(ws4, o);
        if ((lane >> 4) == (w - 4)) {          // wave 4+i writes t in [64i,64i+64)
          float rs = __builtin_amdgcn_rcpf(ws4);
          float4 po = {p0 * rs, p1 * rs, p2 * rs, p3 * rs};
          *(float4*)(&outb[(size_t)(step - 1) * TT + 4 * lane]) = po;
        }
      }
    }
    if ((lane & 32) == 0 && w < 4) {   // gates: unit m=32w+lane, all 4 gates
      float z0 = bbg[0] + ptr0 * wkA[0] + ptr1 * wkB[0];
      float z1 = bbg[1] + ptr0 * wkA[1] + ptr1 * wkB[1];
      float z2 = bbg[2] + ptr0 * wkA[2] + ptr1 * wkB[2];
      float z3 = bbg[3] + ptr0 * wkA[3] + ptr1 * wkB[3];
      #pragma unroll
      for (int q = 0; q < 4; ++q) {
        z0 += zpart[q * 512 + 0 * HH + m];
        z1 += zpart[q * 512 + 1 * HH + m];
        z2 += zpart[q * 512 + 2 * HH + m];
        z3 += zpart[q * 512 + 3 * HH + m];
      }
      float ig = fast_sigmoid(z0);
      float fg = fast_sigmoid(z1);
      float gg = fast_tanh(z2);
      float og = fast_sigmoid(z3);
      c = fg * c + ig * gg;
      hbuf[m] = og * fast_tanh(c);
    }
    __syncthreads();                 // (W1) h_step visible

    // ==== fat window: C (wave-local u_k octet) + D + Apre ====
    float Uk;
    {
      float cp0 = 0.0f, cp1 = 0.0f;
      const float4* h4 = (const float4*)(hbuf + 16 * jq8);
      #pragma unroll
      for (int i4 = 0; i4 < 4; ++i4) {
        float4 hv = h4[i4];
        cp0 += hv.x * w2loc[4 * i4 + 0];
        cp1 += hv.y * w2loc[4 * i4 + 1];
        cp0 += hv.z * w2loc[4 * i4 + 2];
        cp1 += hv.w * w2loc[4 * i4 + 3];
      }
      float csum = cp0 + cp1;
      csum += __shfl_xor(csum, 8);
      csum += __shfl_xor(csum, 16);
      csum += __shfl_xor(csum, 32);
      Uk = __builtin_amdgcn_exp2f(csum * C2);
    }
    // D: wave w, k in [8w,+8); lane owns t in {lane,64+,128+,192+}
    {
      float uL[8];
      #pragma unroll
      for (int i = 0; i < 8; ++i) uL[i] = rdlane(Uk, i);
      #pragma unroll
      for (int tt = 0; tt < 4; ++tt) {
        const float* Er = &E[(64 * tt + lane) * EST + 8 * w];
        float4 e0 = *(const float4*)(Er + 0);
        float4 e1 = *(const float4*)(Er + 4);
        float a0 = 0.0f, a1 = 0.0f;
        float t0, t1, n;
        t0 = fmaf(e0.x, uL[0], 1.0f); t1 = fmaf(e0.y, uL[1], 1.0f);
        n  = fmaf(vL[1], t0, vL[0] * t1);
        a0 = fmaf(n, __builtin_amdgcn_rcpf(t0 * t1), a0);
        t0 = fmaf(e0.z, uL[2], 1.0f); t1 = fmaf(e0.w, uL[3], 1.0f);
        n  = fmaf(vL[3], t0, vL[2] * t1);
        a1 = fmaf(n, __builtin_amdgcn_rcpf(t0 * t1), a1);
        t0 = fmaf(e1.x, uL[4], 1.0f); t1 = fmaf(e1.y, uL[5], 1.0f);
        n  = fmaf(vL[5], t0, vL[4] * t1);
        a0 = fmaf(n, __builtin_amdgcn_rcpf(t0 * t1), a0);
        t0 = fmaf(e1.z, uL[6], 1.0f); t1 = fmaf(e1.w, uL[7], 1.0f);
        n  = fmaf(vL[7], t0, vL[6] * t1);
        a1 = fmaf(n, __builtin_amdgcn_rcpf(t0 * t1), a1);
        scp[w * SCPS + 64 * tt + lane] = a0 + a1;
      }
    }
    // Apre: zpart = h_step @ Wr; h via broadcast b128 reads (kq wave-uniform)
    {
      const float4* h4 = (const float4*)(hbuf + 32 * kq);
      float2 zac = {0.f, 0.f};
      #pragma unroll
      for (int i4 = 0; i4 < 8; ++i4) {
        float4 hv = h4[i4];
        zac.x += hv.x * wr2[4 * i4 + 0].x; zac.y += hv.x * wr2[4 * i4 + 0].y;
        zac.x += hv.y * wr2[4 * i4 + 1].x; zac.y += hv.y * wr2[4 * i4 + 1].y;
        zac.x += hv.z * wr2[4 * i4 + 2].x; zac.y += hv.z * wr2[4 * i4 + 2].y;
        zac.x += hv.w * wr2[4 * i4 + 3].x; zac.y += hv.w * wr2[4 * i4 + 3].y;
      }
      *(float2*)(&zpart[kq * 512 + 2 * cs2]) = zac;
    }
    __syncthreads();                 // (W3) scp + zpart visible
  }

  // ---------------- peel: reduce + store final row (step 255) ----------------
  if (w >= 4 && w < 8) {
    float4 sc = {0.f, 0.f, 0.f, 0.f};
    #pragma unroll
    for (int q = 0; q < 16; ++q) {
      const float4 v = *(const float4*)(&scp[q * SCPS + 4 * lane]);
      sc.x += v.x; sc.y += v.y; sc.z += v.z; sc.w += v.w;
    }
    sc.x += svr; sc.y += svr; sc.z += svr; sc.w += svr;
    float p0 = __builtin_amdgcn_exp2f((sc.x - 12.0f) * L2E);
    float p1 = __builtin_amdgcn_exp2f((sc.y - 12.0f) * L2E);
    float p2 = __builtin_amdgcn_exp2f((sc.z - 12.0f) * L2E);
    float p3 = __builtin_amdgcn_exp2f((sc.w - 12.0f) * L2E);
    float ws4 = (p0 + p1) + (p2 + p3);
    #pragma unroll
    for (int o = 1; o < 64; o <<= 1) ws4 += __shfl_xor(ws4, o);
    if ((lane >> 4) == (w - 4)) {
      float rs = __builtin_amdgcn_rcpf(ws4);
      float4 po = {p0 * rs, p1 * rs, p2 * rs, p3 * rs};
      *(float4*)(&outb[(size_t)255 * TT + 4 * lane]) = po;
    }
  }
}

extern "C" void kernel_launch(void* const* d_in, const int* in_sizes, int n_in,
                              void* d_out, int out_size, void* d_ws, size_t ws_size,
                              hipStream_t stream) {
  (void)in_sizes; (void)n_in; (void)d_ws; (void)ws_size; (void)out_size;
  const float* x    = (const float*)d_in[0];
  const float* enc  = (const float*)d_in[1];
  const float* h0   = (const float*)d_in[2];
  const float* c0   = (const float*)d_in[3];
  const float* W1   = (const float*)d_in[4];
  const float* W2   = (const float*)d_in[5];
  const float* V    = (const float*)d_in[6];
  const float* Wk   = (const float*)d_in[7];
  const float* Wr   = (const float*)d_in[8];
  const float* bias = (const float*)d_in[9];
  float* out = (float*)d_out;

  decoder_kernel<<<64, 1024, 0, stream>>>(x, enc, h0, c0, W1, W2, V, Wk, Wr, bias, out);
}